// Round 3
// baseline (68.012 us; speedup 1.0000x reference)
//
#include <hip/hip_runtime.h>

#define EPSF 1e-8f
#define R2C 0.0025f   // 0.05^2
#define NJ 32         // j-chunk partials for k_pairs

// ---------------- ws float layout ----------------
// scal[0..2]  : sum of head-masked points (x,y,z)
// scal[3]     : n_head
// scal[4]     : pv, scal[5]: gv, scal[6]: nb
// scal[7..12] : cov sums xx,xy,xz,yy,yz,zz
// scal[13]    : sum d*hf      scal[14]: sum hf*d^2
// scal[15]    : max d (float bits via atomicMax int)
// scal[16]    : sum_var       scal[17]: ni
// int slots   : [20] nc (compaction counter), [21] done-counter
// ws+64        : cpos4[n] (float4: -2x,-2y,-2z,sq)  [compacted boundary pts]
// ws+64+4n     : cxv2[n]  (float2: v, v^2)
// ws+64+6n     : partials cnt_p[NJ][n], sx_p[NJ][n], sx2_p[NJ][n]
// total need: (64 + 6n + 3*NJ*n)*4 B ~= 3.4 MB << ws_size (~268 MB)

__device__ inline int read_mask(const void* p, int i, int isInt) {
    if (isInt) return ((const int*)p)[i] != 0;
    return ((const unsigned char*)p)[i] != 0;
}

__device__ inline float wave_sum(float v) {
    #pragma unroll
    for (int o = 32; o > 0; o >>= 1) v += __shfl_down(v, o, 64);
    return v;
}
__device__ inline float wave_max(float v) {
    #pragma unroll
    for (int o = 32; o > 0; o >>= 1) v = fmaxf(v, __shfl_down(v, o, 64));
    return v;
}

// K1: mask-layout detect (block-local, scans first 1KB = 256 words of each
// mask; byte layout shows nonzero upper bytes unless first 1024 bools are
// all false, p ~ 2^-768), per-point sums, boundary compaction.
__global__ void k_prep(const float* __restrict__ pts, const float* __restrict__ segp,
                       const void* bm, const void* hm, const void* pm, const void* gm,
                       float* __restrict__ ws, int n) {
    __shared__ int bad[4];
    int tid = threadIdx.x;
    if (tid < 4) bad[tid] = 0;
    __syncthreads();
    const void* ms[4] = {bm, hm, pm, gm};
    #pragma unroll
    for (int m = 0; m < 4; ++m) {
        unsigned w = ((const unsigned*)ms[m])[tid & 255];
        if (w & 0xFFFFFF00u) atomicOr(&bad[m], 1);
    }
    __syncthreads();

    int i = blockIdx.x * blockDim.x + tid;
    if (i >= n) return;
    float x = pts[3*i], y = pts[3*i+1], z = pts[3*i+2];
    float v = segp[3*i+2];
    int b = read_mask(bm, i, !bad[0]);
    int h = read_mask(hm, i, !bad[1]);
    int p = read_mask(pm, i, !bad[2]);
    int g = read_mask(gm, i, !bad[3]);

    float hf = h ? 1.0f : 0.0f;
    float vals[7] = { hf*x, hf*y, hf*z, hf, (float)p, (float)g, (float)b };
    #pragma unroll
    for (int k = 0; k < 7; ++k) {
        float s = wave_sum(vals[k]);
        if ((tid & 63) == 0) atomicAdd(&ws[k], s);
    }

    // compact boundary points (order across waves is atomic-racy but the
    // downstream sums are order-insensitive up to fp rounding)
    float4* cpos = (float4*)(ws + 64);
    float2* cxv  = (float2*)(ws + 64 + 4*(size_t)n);
    unsigned long long ball = __ballot(b != 0);
    int lane = tid & 63;
    int cnt  = __popcll(ball);
    int pre  = __popcll(ball & ((1ull << lane) - 1ull));
    int base = 0;
    if (lane == 0 && cnt > 0) base = atomicAdd((int*)ws + 20, cnt);
    base = __shfl(base, 0, 64);
    if (b) {
        int r = base + pre;
        float sq = x*x + y*y + z*z;
        cpos[r] = make_float4(-2.0f*x, -2.0f*y, -2.0f*z, sq);
        cxv[r]  = make_float2(v, v*v);
    }
}

// K2: O(nc^2) over compacted boundary points. grid (n/256, NJ).
__global__ void k_pairs(float* __restrict__ ws, int n) {
    const float4* __restrict__ cpos = (const float4*)(ws + 64);
    const float2* __restrict__ cxv  = (const float2*)(ws + 64 + 4*(size_t)n);
    float* __restrict__ outb = ws + 64 + 6*(size_t)n;
    int nc = ((const int*)ws)[20];
    int tid = threadIdx.x;
    int bx = blockIdx.x, c = blockIdx.y;
    if (bx * 256 >= nc) return;          // whole block inactive
    int r = bx * 256 + tid;
    bool act = r < nc;
    float4 pi = act ? cpos[r] : make_float4(0.f, 0.f, 0.f, 0.f);
    float xi = -0.5f * pi.x, yi = -0.5f * pi.y, zi = -0.5f * pi.z;
    float sqi = pi.w;
    float ci = 0.f, s1 = 0.f, s2 = 0.f;
    __shared__ float4 t4[256];
    __shared__ float2 tv[256];
    int T = (nc + 255) >> 8;             // number of 256-wide j-tiles
    for (int t = c; t < T; t += NJ) {
        int j = (t << 8) + tid;
        __syncthreads();
        if (j < nc) { t4[tid] = cpos[j]; tv[tid] = cxv[j]; }
        else        { t4[tid] = make_float4(0.f,0.f,0.f,1e9f); tv[tid] = make_float2(0.f,0.f); }
        __syncthreads();
        #pragma unroll 8
        for (int k = 0; k < 256; ++k) {
            float4 pj = t4[k];
            float2 vv = tv[k];
            float tacc = fmaf(pj.x, xi, pj.w);
            tacc = fmaf(pj.y, yi, tacc);
            tacc = fmaf(pj.z, zi, tacc);
            float d2 = tacc + sqi;
            float m = (d2 < R2C) ? 1.0f : 0.0f;
            ci += m;
            s1 = fmaf(m, vv.x, s1);
            s2 = fmaf(m, vv.y, s2);
        }
    }
    if (act) {                            // chunks with zero tiles still write 0
        outb[(size_t)c * n + r]          = ci;
        outb[(size_t)(NJ + c) * n + r]   = s1;
        outb[(size_t)(2*NJ + c) * n + r] = s2;
    }
}

// K3: fused passB (cov/conn point reductions) + passD (partial reduce) +
// passE (final scalar assembly via last-block-done).
__global__ void k_final(const float* __restrict__ pts, const void* hm,
                        float* __restrict__ ws, float* __restrict__ out, int n) {
    __shared__ int badh;
    __shared__ int last;
    int tid = threadIdx.x;
    if (tid == 0) { badh = 0; last = 0; }
    __syncthreads();
    unsigned w = ((const unsigned*)hm)[tid & 255];
    if (w & 0xFFFFFF00u) atomicOr(&badh, 1);
    __syncthreads();

    float* scal = ws;
    int i = blockIdx.x * blockDim.x + tid;

    // ---- phase 1: center-dependent point reductions (old passB) ----
    float nh = scal[3];
    float inv = (nh > 0.f) ? 1.0f / nh : 0.f;
    float cx = scal[0]*inv, cy = scal[1]*inv, cz = scal[2]*inv;
    float x = pts[3*i], y = pts[3*i+1], z = pts[3*i+2];
    int h = read_mask(hm, i, !badh);
    float m = h ? 1.f : 0.f;
    float dx = x - cx, dy = y - cy, dz = z - cz;
    float d = sqrtf(dx*dx + dy*dy + dz*dz);
    float vals[8] = { m*dx*dx, m*dx*dy, m*dx*dz, m*dy*dy, m*dy*dz, m*dz*dz,
                      m*d, m*d*d };
    #pragma unroll
    for (int k = 0; k < 8; ++k) {
        float s = wave_sum(vals[k]);
        if ((tid & 63) == 0) atomicAdd(&scal[7 + k], s);
    }
    float dm = wave_max(h ? d : 0.f);
    if ((tid & 63) == 0) atomicMax((int*)&scal[15], __float_as_int(dm));

    // ---- phase 2: reduce k_pairs partials (old passD); rows are compacted
    //      boundary points, so include = (cnt > 1) ----
    int nc = ((const int*)ws)[20];
    const float* __restrict__ outb = ws + 64 + 6*(size_t)n;
    float sv = 0.f, nv = 0.f;
    if (i < nc) {
        float c0 = 0.f, a1 = 0.f, a2 = 0.f;
        #pragma unroll
        for (int k = 0; k < NJ; ++k) {
            c0 += outb[(size_t)k * n + i];
            a1 += outb[(size_t)(NJ + k) * n + i];
            a2 += outb[(size_t)(2*NJ + k) * n + i];
        }
        float safe_n = fmaxf(c0, 2.0f);
        float var = (a2 - a1*a1/safe_n) / (safe_n - 1.0f);
        if (c0 > 1.0f) { sv = var; nv = 1.0f; }
    }
    sv = wave_sum(sv); nv = wave_sum(nv);
    if ((tid & 63) == 0) { atomicAdd(&scal[16], sv); atomicAdd(&scal[17], nv); }

    // ---- phase 3: last block assembles the output ----
    __syncthreads();                  // all this block's atomics issued+drained
    if (tid == 0) {
        __threadfence();
        int prev = atomicAdd((int*)ws + 21, 1);
        if (prev == (int)gridDim.x - 1) last = 1;
    }
    __syncthreads();
    if (!last || tid != 0) return;

    // atomic reads => coherent view of all blocks' atomics across XCDs
    float s0  = atomicAdd(&scal[0], 0.f), s1_ = atomicAdd(&scal[1], 0.f);
    float s2_ = atomicAdd(&scal[2], 0.f), nh2 = atomicAdd(&scal[3], 0.f);
    float pv  = atomicAdd(&scal[4], 0.f), gv  = atomicAdd(&scal[5], 0.f);
    float nbm = atomicAdd(&scal[6], 0.f);
    float cxx = atomicAdd(&scal[7], 0.f), cxy = atomicAdd(&scal[8], 0.f);
    float cxz = atomicAdd(&scal[9], 0.f), cyy = atomicAdd(&scal[10], 0.f);
    float cyz = atomicAdd(&scal[11], 0.f), czz = atomicAdd(&scal[12], 0.f);
    float sd  = atomicAdd(&scal[13], 0.f), sd2 = atomicAdd(&scal[14], 0.f);
    float maxd = __int_as_float(atomicAdd((int*)&scal[15], 0));
    float svv = atomicAdd(&scal[16], 0.f), niv = atomicAdd(&scal[17], 0.f);
    (void)s0; (void)s1_; (void)s2_;

    // ellipsoid shape loss (closed-form symmetric 3x3 eigvals, double)
    float el = 0.0f;
    if (nh2 >= 10.0f) {
        double nn  = (double)nh2;
        double axx = cxx/nn, axy = cxy/nn, axz = cxz/nn;
        double ayy = cyy/nn, ayz = cyz/nn, azz = czz/nn;
        double p1 = axy*axy + axz*axz + ayz*ayz;
        double q  = (axx + ayy + azz) / 3.0;
        double p2 = (axx-q)*(axx-q) + (ayy-q)*(ayy-q) + (azz-q)*(azz-q) + 2.0*p1;
        double e0, e2;
        if (p2 < 1e-300) { e0 = e2 = q; }
        else {
            double p = sqrt(p2 / 6.0);
            double bxx = (axx-q)/p, byy = (ayy-q)/p, bzz = (azz-q)/p;
            double bxy = axy/p, bxz = axz/p, byz = ayz/p;
            double detB = bxx*(byy*bzz - byz*byz) - bxy*(bxy*bzz - byz*bxz)
                        + bxz*(bxy*byz - byy*bxz);
            double r2 = fmin(1.0, fmax(-1.0, detB * 0.5));
            double phi = acos(r2) / 3.0;
            e2 = q + 2.0*p*cos(phi);                       // largest
            e0 = q + 2.0*p*cos(phi + 2.0943951023931953);  // smallest
        }
        double e1 = 3.0*q - e2 - e0;
        double ra = e1/(e2 + (double)EPSF) - 1.0;
        double rc = e0/(e2 + (double)EPSF) - 1.0;
        el = (float)(ra*ra + rc*rc);
    }
    // size consistency
    float diff = pv - gv;
    float vol = diff * diff;
    float rel = fabsf(diff) / (gv > 0.0f ? gv : 1.0f);
    float sc = (gv > 0.0f) ? vol + 0.5f*rel : vol;
    // surface smoothness
    float mean_var = svv / fmaxf(niv, 1.0f);
    float ss = ((nbm >= 5.0f) && (niv > 0.0f)) ? mean_var : 0.0f;
    // connectivity
    float conn = 0.0f;
    if (nh2 >= 5.0f) {
        float var = (sd2 - sd*sd/nh2) / (nh2 - 1.0f);
        conn = var / (maxd + EPSF);
    }
    out[0] = el + sc + ss + conn;
}

extern "C" void kernel_launch(void* const* d_in, const int* in_sizes, int n_in,
                              void* d_out, int out_size, void* d_ws, size_t ws_size,
                              hipStream_t stream) {
    const float* points = (const float*)d_in[0];
    const float* segp   = (const float*)d_in[1];
    const void*  bmask  = d_in[2];
    const void*  hmask  = d_in[3];
    const void*  pmask  = d_in[4];
    const void*  gmask  = d_in[5];
    float* ws  = (float*)d_ws;
    float* out = (float*)d_out;
    int n = in_sizes[2];            // 8192
    int nb = (n + 255) / 256;

    hipMemsetAsync(d_ws, 0, 256, stream);   // zero scal + counters
    k_prep<<<nb, 256, 0, stream>>>(points, segp, bmask, hmask, pmask, gmask, ws, n);
    k_pairs<<<dim3(nb, NJ), 256, 0, stream>>>(ws, n);
    k_final<<<nb, 256, 0, stream>>>(points, hmask, ws, out, n);
}

// Round 4
// 35.120 us; speedup vs baseline: 1.9366x; 1.9366x over previous
//
#include <hip/hip_runtime.h>

#define EPSF 1e-8f
#define R2C  0.0025f   // 0.05^2
#define NJ   32        // j-chunk partial sets

// ---------------- ws float-index layout ----------------
// [0]                   : ticket (unsigned, ACCUMULATING across launches —
//                         "prev % grid == grid-1" fires exactly once per
//                         launch for any start value, so no reset needed)
// [64  + blk*16 + 0..6] : k_prep per-block rows {hx,hy,hz,nh,pv,gv,nb}
// [1024 + blk*16 + 0..11]: k_final per-block rows {cov6, sd, sd2, maxd, sv, nv, pad}
// [4096]                : pos4[n]  (float4: -2x,-2y,-2z, sq or sq+1000 sentinel)
// [4096+4n]             : xv2[n]   (float2: v, v^2)
// [4096+6n]             : pair partials cnt[NJ][n], sx[NJ][n], sx2[NJ][n]
// total ~3.4 MB << ws_size. All regions fully rewritten every launch.

__device__ inline int read_mask(const void* p, int i, int isInt) {
    if (isInt) return ((const int*)p)[i] != 0;
    return ((const unsigned char*)p)[i] != 0;
}
__device__ inline float wave_sum(float v) {
    #pragma unroll
    for (int o = 32; o > 0; o >>= 1) v += __shfl_down(v, o, 64);
    return v;
}
__device__ inline float wave_max(float v) {
    #pragma unroll
    for (int o = 32; o > 0; o >>= 1) v = fmaxf(v, __shfl_down(v, o, 64));
    return v;
}

// K1: mask-layout detect + per-point sums (per-block rows, LDS reduce only)
// + pos4/xv2 staging with boundary sentinel.
__global__ void k_prep(const float* __restrict__ pts, const float* __restrict__ segp,
                       const void* bm, const void* hm, const void* pm, const void* gm,
                       float* __restrict__ ws, int n) {
    __shared__ int bad[4];
    __shared__ float facc[8];
    int tid = threadIdx.x, lane = tid & 63;
    if (tid < 4) bad[tid] = 0;
    if (tid < 8) facc[tid] = 0.f;
    __syncthreads();
    const void* ms[4] = {bm, hm, pm, gm};
    #pragma unroll
    for (int m = 0; m < 4; ++m) {
        unsigned w = ((const unsigned*)ms[m])[tid & 255];
        if (w & 0xFFFFFF00u) atomicOr(&bad[m], 1);
    }
    __syncthreads();

    int i = blockIdx.x * 256 + tid;
    int ic = min(i, n - 1);
    float act = (i < n) ? 1.f : 0.f;
    float x = pts[3*ic], y = pts[3*ic+1], z = pts[3*ic+2];
    float v = segp[3*ic+2];
    int b = read_mask(bm, ic, !bad[0]);
    int h = read_mask(hm, ic, !bad[1]);
    int p = read_mask(pm, ic, !bad[2]);
    int g = read_mask(gm, ic, !bad[3]);
    float sq = x*x + y*y + z*z;

    if (i < n) {
        float4* pos4 = (float4*)(ws + 4096);
        float2* xv2  = (float2*)(ws + 4096 + 4*(size_t)n);
        // non-boundary: sq+1000 => d2 >= ~994 >> R2 for every pair (exact mask)
        pos4[i] = make_float4(-2.f*x, -2.f*y, -2.f*z, b ? sq : sq + 1000.f);
        xv2[i]  = make_float2(v, v*v);
    }
    float hf = (h ? 1.f : 0.f) * act;
    float vals[7] = { hf*x, hf*y, hf*z, hf,
                      act*(float)p, act*(float)g, act*(float)b };
    #pragma unroll
    for (int k = 0; k < 7; ++k) {
        float s = wave_sum(vals[k]);
        if (lane == 0) atomicAdd(&facc[k], s);   // LDS atomic: on-CU, cheap
    }
    __syncthreads();
    if (tid < 8) ws[64 + blockIdx.x*16 + tid] = (tid < 7) ? facc[tid] : 0.f;
}

// K2: O(N^2) pair sweep, atomic-free. grid (nb, NJ); per-(i,chunk) partials.
__global__ void k_pairs(float* __restrict__ ws, int n, int nb) {
    const float4* __restrict__ pos4 = (const float4*)(ws + 4096);
    const float2* __restrict__ xv2  = (const float2*)(ws + 4096 + 4*(size_t)n);
    float* __restrict__ outb = ws + 4096 + 6*(size_t)n;
    int tid = threadIdx.x;
    int i = blockIdx.x * 256 + tid;
    int c = blockIdx.y;
    __shared__ float4 t4[256];
    __shared__ float2 tv[256];
    float4 pi = pos4[min(i, n-1)];
    float xi = -0.5f*pi.x, yi = -0.5f*pi.y, zi = -0.5f*pi.z;
    float sqi = pi.w;
    float ci = 0.f, s1 = 0.f, s2 = 0.f;
    for (int t = c; t < nb; t += NJ) {
        int j = t*256 + tid;
        __syncthreads();
        if (j < n) { t4[tid] = pos4[j]; tv[tid] = xv2[j]; }
        else       { t4[tid] = make_float4(0.f,0.f,0.f,1e9f); tv[tid] = make_float2(0.f,0.f); }
        __syncthreads();
        #pragma unroll 8
        for (int k = 0; k < 256; ++k) {
            float4 pj = t4[k];
            float2 vv = tv[k];
            float acc = fmaf(pj.x, xi, pj.w);
            acc = fmaf(pj.y, yi, acc);
            acc = fmaf(pj.z, zi, acc);
            float d2 = acc + sqi;
            float m = (d2 < R2C) ? 1.f : 0.f;
            ci += m;
            s1 = fmaf(m, vv.x, s1);
            s2 = fmaf(m, vv.y, s2);
        }
    }
    if (i < n) {
        outb[(size_t)c*n + i]          = ci;
        outb[(size_t)(NJ + c)*n + i]   = s1;
        outb[(size_t)(2*NJ + c)*n + i] = s2;
    }
}

// K3: center-dependent reductions + partial reduce + last-block assembly.
__global__ void k_final(const float* __restrict__ pts, const void* bm, const void* hm,
                        float* __restrict__ ws, float* __restrict__ out, int n, int nb) {
    __shared__ int badb, badh, lastf, bmax;
    __shared__ float ctr[8];
    __shared__ float bacc[12];
    int tid = threadIdx.x, lane = tid & 63;
    if (tid == 0) { badb = 0; badh = 0; lastf = 0; bmax = 0; }
    if (tid < 12) bacc[tid] = 0.f;
    __syncthreads();
    unsigned wb = ((const unsigned*)bm)[tid & 255];
    unsigned wh = ((const unsigned*)hm)[tid & 255];
    if (wb & 0xFFFFFF00u) atomicOr(&badb, 1);
    if (wh & 0xFFFFFF00u) atomicOr(&badh, 1);

    // sum k_prep rows (nb <= 64) -> global counts & head centroid
    if (tid < 64) {
        float4 A = make_float4(0.f,0.f,0.f,0.f), B = make_float4(0.f,0.f,0.f,0.f);
        if (tid < nb) {
            A = *(const float4*)(ws + 64 + tid*16);
            B = *(const float4*)(ws + 64 + tid*16 + 4);
        }
        #pragma unroll
        for (int o = 32; o > 0; o >>= 1) {
            A.x += __shfl_down(A.x,o,64); A.y += __shfl_down(A.y,o,64);
            A.z += __shfl_down(A.z,o,64); A.w += __shfl_down(A.w,o,64);
            B.x += __shfl_down(B.x,o,64); B.y += __shfl_down(B.y,o,64);
            B.z += __shfl_down(B.z,o,64);
        }
        if (tid == 0) { ctr[0]=A.x; ctr[1]=A.y; ctr[2]=A.z; ctr[3]=A.w;
                        ctr[4]=B.x; ctr[5]=B.y; ctr[6]=B.z; ctr[7]=0.f; }
    }
    __syncthreads();

    float nh = ctr[3];
    float inv = (nh > 0.f) ? 1.f/nh : 0.f;
    float cx = ctr[0]*inv, cy = ctr[1]*inv, cz = ctr[2]*inv;
    int i = blockIdx.x*256 + tid;
    int ic = min(i, n-1);
    float act = (i < n) ? 1.f : 0.f;
    float x = pts[3*ic], y = pts[3*ic+1], z = pts[3*ic+2];
    int h = read_mask(hm, ic, !badh);
    float m = (h ? 1.f : 0.f) * act;
    float dx = x-cx, dy = y-cy, dz = z-cz;
    float d = sqrtf(dx*dx + dy*dy + dz*dz);
    float vals[8] = { m*dx*dx, m*dx*dy, m*dx*dz, m*dy*dy, m*dy*dz, m*dz*dz,
                      m*d, m*d*d };
    #pragma unroll
    for (int k = 0; k < 8; ++k) {
        float s = wave_sum(vals[k]);
        if (lane == 0) atomicAdd(&bacc[k], s);
    }
    float dm = wave_max(m > 0.f ? d : 0.f);
    if (lane == 0) atomicMax(&bmax, __float_as_int(dm));

    // reduce this i's pair partials
    const float* __restrict__ outb = ws + 4096 + 6*(size_t)n;
    float sv = 0.f, nv = 0.f;
    if (i < n) {
        float c0 = 0.f, a1 = 0.f, a2 = 0.f;
        #pragma unroll
        for (int k = 0; k < NJ; ++k) {
            c0 += outb[(size_t)k*n + i];
            a1 += outb[(size_t)(NJ + k)*n + i];
            a2 += outb[(size_t)(2*NJ + k)*n + i];
        }
        int b = read_mask(bm, i, !badb);
        float safe_n = fmaxf(c0, 2.f);
        float var = (a2 - a1*a1/safe_n) / (safe_n - 1.f);
        if (b && c0 > 1.f) { sv = var; nv = 1.f; }
    }
    sv = wave_sum(sv); nv = wave_sum(nv);
    if (lane == 0) { atomicAdd(&bacc[9], sv); atomicAdd(&bacc[10], nv); }
    __syncthreads();

    // publish per-block row at the coherent point (atomicExch), then ticket
    float* row = ws + 1024 + blockIdx.x*16;
    if (tid < 12) {
        float val = (tid == 8) ? __int_as_float(bmax) : bacc[tid];
        atomicExch((int*)&row[tid], __float_as_int(val));
    }
    if (tid == 0) {
        __threadfence();
        unsigned prev = atomicAdd((unsigned*)ws, 1u);
        if (prev % (unsigned)gridDim.x == (unsigned)gridDim.x - 1u) lastf = 1;
    }
    __syncthreads();
    if (!lastf) return;

    // last block: gather all rows with atomic loads (32 distinct lines, parallel)
    if (tid < 12) bacc[tid] = 0.f;
    if (tid == 0) bmax = 0;
    __syncthreads();
    for (int t = tid; t < nb*12; t += 256) {
        int r = t / 12, col = t % 12;
        int bits = atomicOr((int*)&ws[1024 + r*16 + col], 0);
        if (col == 8) atomicMax(&bmax, bits);
        else          atomicAdd(&bacc[col], __int_as_float(bits));
    }
    __syncthreads();
    if (tid != 0) return;

    float cxx=bacc[0], cxy=bacc[1], cxz=bacc[2];
    float cyy=bacc[3], cyz=bacc[4], czz=bacc[5];
    float sd=bacc[6], sd2=bacc[7], svv=bacc[9], niv=bacc[10];
    float maxd = __int_as_float(bmax);
    float pv = ctr[4], gv = ctr[5], nbm = ctr[6];

    // ellipsoid shape loss (closed-form symmetric 3x3 eigvals, double)
    float el = 0.0f;
    if (nh >= 10.0f) {
        double nn  = (double)nh;
        double axx = cxx/nn, axy = cxy/nn, axz = cxz/nn;
        double ayy = cyy/nn, ayz = cyz/nn, azz = czz/nn;
        double p1 = axy*axy + axz*axz + ayz*ayz;
        double q  = (axx + ayy + azz) / 3.0;
        double p2 = (axx-q)*(axx-q) + (ayy-q)*(ayy-q) + (azz-q)*(azz-q) + 2.0*p1;
        double e0, e2;
        if (p2 < 1e-300) { e0 = e2 = q; }
        else {
            double p = sqrt(p2 / 6.0);
            double bxx = (axx-q)/p, byy = (ayy-q)/p, bzz = (azz-q)/p;
            double bxy = axy/p, bxz = axz/p, byz = ayz/p;
            double detB = bxx*(byy*bzz - byz*byz) - bxy*(bxy*bzz - byz*bxz)
                        + bxz*(bxy*byz - byy*bxz);
            double r2 = fmin(1.0, fmax(-1.0, detB * 0.5));
            double phi = acos(r2) / 3.0;
            e2 = q + 2.0*p*cos(phi);                       // largest
            e0 = q + 2.0*p*cos(phi + 2.0943951023931953);  // smallest
        }
        double e1 = 3.0*q - e2 - e0;
        double ra = e1/(e2 + (double)EPSF) - 1.0;
        double rc = e0/(e2 + (double)EPSF) - 1.0;
        el = (float)(ra*ra + rc*rc);
    }
    // size consistency
    float diff = pv - gv;
    float vol = diff * diff;
    float rel = fabsf(diff) / (gv > 0.0f ? gv : 1.0f);
    float sc = (gv > 0.0f) ? vol + 0.5f*rel : vol;
    // surface smoothness
    float mean_var = svv / fmaxf(niv, 1.0f);
    float ss = ((nbm >= 5.0f) && (niv > 0.0f)) ? mean_var : 0.0f;
    // connectivity
    float conn = 0.0f;
    if (nh >= 5.0f) {
        float var = (sd2 - sd*sd/nh) / (nh - 1.0f);
        conn = var / (maxd + EPSF);
    }
    out[0] = el + sc + ss + conn;
}

extern "C" void kernel_launch(void* const* d_in, const int* in_sizes, int n_in,
                              void* d_out, int out_size, void* d_ws, size_t ws_size,
                              hipStream_t stream) {
    const float* points = (const float*)d_in[0];
    const float* segp   = (const float*)d_in[1];
    const void*  bmask  = d_in[2];
    const void*  hmask  = d_in[3];
    const void*  pmask  = d_in[4];
    const void*  gmask  = d_in[5];
    float* ws  = (float*)d_ws;
    float* out = (float*)d_out;
    int n = in_sizes[2];            // 8192
    int nb = (n + 255) / 256;       // 32

    k_prep<<<nb, 256, 0, stream>>>(points, segp, bmask, hmask, pmask, gmask, ws, n);
    k_pairs<<<dim3(nb, NJ), 256, 0, stream>>>(ws, n, nb);
    k_final<<<nb, 256, 0, stream>>>(points, bmask, hmask, ws, out, n, nb);
}